// Round 1
// baseline (394.166 us; speedup 1.0000x reference)
//
#include <hip/hip_runtime.h>
#include <math.h>

#define BB 4
#define SS 1024
#define XX 1024
#define CC 8
#define DD 2
#define WIDTH 16
#define DEPTH 4

// tanh(x) = sign(x) * (1-e)/(1+e), e = exp(-2|x|)
__device__ __forceinline__ float fast_tanh(float v) {
    float ax = __builtin_fabsf(v);
    float e  = __expf(-2.0f * ax);                       // v_exp_f32 path
    float t  = (1.0f - e) * __builtin_amdgcn_rcpf(1.0f + e);
    return __builtin_copysignf(t, v);
}

__global__ __launch_bounds__(256) void ccl_kernel(
    const float* __restrict__ yu,     // (B,S,C+D)
    const float* __restrict__ x,      // (B,X,D)
    const float* __restrict__ W_in,   // (1,W)
    const float* __restrict__ b_in,   // (W)
    const float* __restrict__ W_hid,  // (DEPTH,W,W)
    const float* __restrict__ b_hid,  // (DEPTH,W)
    const float* __restrict__ W_out,  // (W,1)
    const float* __restrict__ b_out,  // (1)
    float* __restrict__ out)          // (B,X,C)
{
    const int bx = blockIdx.x;
    const int b  = bx >> 10;          // X = 1024
    const int xi = bx & (XX - 1);

    // query point (uniform per block -> scalar regs)
    const float px0 = x[((size_t)b * XX + xi) * DD + 0];
    const float px1 = x[((size_t)b * XX + xi) * DD + 1];

    // small weights (uniform -> SGPRs)
    float win[WIDTH], bin[WIDTH], wout[WIDTH];
#pragma unroll
    for (int j = 0; j < WIDTH; ++j) {
        win[j]  = W_in[j];
        bin[j]  = b_in[j];
        wout[j] = W_out[j];
    }
    const float bo = b_out[0];

    float acc[CC];
#pragma unroll
    for (int c = 0; c < CC; ++c) acc[c] = 0.0f;

    for (int s = threadIdx.x; s < SS; s += 256) {
        const float* yup = yu + ((size_t)b * SS + s) * (CC + DD);
        // 40B stride, 8B aligned -> five dwordx2 loads
        const float2* yp2 = reinterpret_cast<const float2*>(yup);
        float2 a0 = yp2[0], a1 = yp2[1], a2 = yp2[2], a3 = yp2[3], a4 = yp2[4];

        const float d0 = px0 - a4.x;
        const float d1 = px1 - a4.y;
        const float r  = d0 * d0 + d1 * d1;

        float h[WIDTH];
#pragma unroll
        for (int j = 0; j < WIDTH; ++j) h[j] = fmaf(r, win[j], bin[j]);

#pragma unroll
        for (int l = 0; l < DEPTH; ++l) {
            const float* W  = W_hid + l * WIDTH * WIDTH;
            const float* bb = b_hid + l * WIDTH;
            float pre[WIDTH];
#pragma unroll
            for (int j = 0; j < WIDTH; ++j) pre[j] = bb[j];
#pragma unroll
            for (int i = 0; i < WIDTH; ++i) {
                const float hi = h[i];
#pragma unroll
                for (int j = 0; j < WIDTH; ++j)
                    pre[j] = fmaf(hi, W[i * WIDTH + j], pre[j]);
            }
#pragma unroll
            for (int j = 0; j < WIDTH; ++j) h[j] += fast_tanh(pre[j]);
        }

        float k = bo;
#pragma unroll
        for (int j = 0; j < WIDTH; ++j) k = fmaf(h[j], wout[j], k);

        const float u[CC] = {a0.x, a0.y, a1.x, a1.y, a2.x, a2.y, a3.x, a3.y};
#pragma unroll
        for (int c = 0; c < CC; ++c) acc[c] = fmaf(k, u[c], acc[c]);
    }

    // wave reduction (width 64)
#pragma unroll
    for (int c = 0; c < CC; ++c) {
        float v = acc[c];
#pragma unroll
        for (int off = 32; off > 0; off >>= 1)
            v += __shfl_down(v, off, 64);
        acc[c] = v;
    }

    __shared__ float red[4][CC];
    const int lane = threadIdx.x & 63;
    const int wv   = threadIdx.x >> 6;
    if (lane == 0) {
#pragma unroll
        for (int c = 0; c < CC; ++c) red[wv][c] = acc[c];
    }
    __syncthreads();
    if (threadIdx.x < CC) {
        const int c = threadIdx.x;
        const float v = red[0][c] + red[1][c] + red[2][c] + red[3][c];
        out[((size_t)b * XX + xi) * CC + c] = v * (1.0f / SS);
    }
}

extern "C" void kernel_launch(void* const* d_in, const int* in_sizes, int n_in,
                              void* d_out, int out_size, void* d_ws, size_t ws_size,
                              hipStream_t stream) {
    const float* yu    = (const float*)d_in[0];
    const float* x     = (const float*)d_in[1];
    const float* W_in  = (const float*)d_in[2];
    const float* b_in  = (const float*)d_in[3];
    const float* W_hid = (const float*)d_in[4];
    const float* b_hid = (const float*)d_in[5];
    const float* W_out = (const float*)d_in[6];
    const float* b_out = (const float*)d_in[7];
    float* out = (float*)d_out;

    dim3 grid(BB * XX);
    dim3 block(256);
    ccl_kernel<<<grid, block, 0, stream>>>(yu, x, W_in, b_in, W_hid, b_hid,
                                           W_out, b_out, out);
}

// Round 2
// 143.969 us; speedup vs baseline: 2.7378x; 2.7378x over previous
//
#include <hip/hip_runtime.h>
#include <math.h>

#define BB 4
#define SS 1024
#define XX 1024
#define CC 8
#define DD 2
#define WIDTH 16
#define DEPTH 4

typedef _Float16 half4 __attribute__((ext_vector_type(4)));
typedef float f32x4 __attribute__((ext_vector_type(4)));

// tanh(v) = copysign(2/(1+exp(-2|v|)) - 1, v)
__device__ __forceinline__ float fast_tanh(float v) {
    float ax = __builtin_fabsf(v);
    float e  = __builtin_amdgcn_exp2f(ax * -2.885390081777927f); // exp(-2|v|) via exp2
    float t  = fmaf(2.0f, __builtin_amdgcn_rcpf(1.0f + e), -1.0f);
    return __builtin_copysignf(t, v);
}

__global__ __launch_bounds__(256) void ccl_kernel(
    const float* __restrict__ yu,     // (B,S,C+D)
    const float* __restrict__ x,      // (B,X,D)
    const float* __restrict__ W_in,   // (1,W)
    const float* __restrict__ b_in,   // (W)
    const float* __restrict__ W_hid,  // (DEPTH,W,W)
    const float* __restrict__ b_hid,  // (DEPTH,W)
    const float* __restrict__ W_out,  // (W,1)
    const float* __restrict__ b_out,  // (1)
    float* __restrict__ out)          // (B,X,C)
{
    const int bx   = blockIdx.x;
    const int b    = bx >> 10;            // X = 1024
    const int xi   = bx & (XX - 1);
    const int tid  = threadIdx.x;
    const int lane = tid & 63;
    const int wv   = tid >> 6;            // wave 0..3
    const int p    = lane & 15;           // point-within-16 (MFMA col n)
    const int g    = lane >> 4;           // lane group 0..3 (MFMA k/row quad)

    // query point (wave-uniform)
    const float px0 = x[((size_t)b * XX + xi) * DD + 0];
    const float px1 = x[((size_t)b * XX + xi) * DD + 1];

    // ---- per-lane weight fragments (loaded once) ----
    // A-operand of layer l: A[m=lane%16][k=4g+i] = W^T[j_out=p][j_in=4g+i]
    //                     = W_hid[l][(4g+i)][p]
    half4 aW[DEPTH];
    f32x4 bh4[DEPTH];          // C-seed: bias in D-layout: b_hid[l][4g+i]
#pragma unroll
    for (int l = 0; l < DEPTH; ++l) {
#pragma unroll
        for (int i = 0; i < 4; ++i) {
            aW[l][i]  = (_Float16)W_hid[l * WIDTH * WIDTH + (4 * g + i) * WIDTH + p];
            bh4[l][i] = b_hid[l * WIDTH + 4 * g + i];
        }
    }
    float win4[4], bin4[4], wout4[4];
#pragma unroll
    for (int i = 0; i < 4; ++i) {
        const int j = 4 * g + i;
        win4[i]  = W_in[j];
        bin4[i]  = b_in[j];
        wout4[i] = W_out[j];
    }
    const float bo = b_out[0];

    float acc0 = 0.0f, acc1 = 0.0f;
    const float* yub = yu + (size_t)b * SS * (CC + DD);

    // 16 iterations: each wave handles 16 points per iteration
    for (int t = 0; t < 16; ++t) {
        const int s = t * 64 + wv * 16 + p;
        const float* row = yub + (size_t)s * (CC + DD);
        const float2 yv = *reinterpret_cast<const float2*>(row + CC);      // y[s][0..1]
        const float2 uv = *reinterpret_cast<const float2*>(row + 2 * g);   // u[s][2g..2g+1]

        const float d0 = px0 - yv.x;
        const float d1 = px1 - yv.y;
        const float r  = fmaf(d0, d0, d1 * d1);

        // h0 in D/B layout: h[i] = h0[feature=4g+i][point=p]
        f32x4 h;
#pragma unroll
        for (int i = 0; i < 4; ++i) h[i] = fmaf(r, win4[i], bin4[i]);

#pragma unroll
        for (int l = 0; l < DEPTH; ++l) {
            half4 hb;
#pragma unroll
            for (int i = 0; i < 4; ++i) hb[i] = (_Float16)h[i];
            // pre^T = W^T * h^T + b  (D-layout == next B-layout)
            f32x4 pre = __builtin_amdgcn_mfma_f32_16x16x16f16(aW[l], hb, bh4[l], 0, 0, 0);
#pragma unroll
            for (int i = 0; i < 4; ++i) h[i] += fast_tanh(pre[i]);
        }

        // k = h . W_out + b_out : partial over this lane's 4 features,
        // then sum the 4 lane-groups (same point p lives in lanes p, p+16, p+32, p+48)
        float kp = 0.0f;
#pragma unroll
        for (int i = 0; i < 4; ++i) kp = fmaf(h[i], wout4[i], kp);
        kp += __shfl_xor(kp, 16, 64);
        kp += __shfl_xor(kp, 32, 64);
        const float k = kp + bo;

        acc0 = fmaf(k, uv.x, acc0);   // channel 2g
        acc1 = fmaf(k, uv.y, acc1);   // channel 2g+1
    }

    // sum over the 16 points (lanes differing in bits 0..3)
#pragma unroll
    for (int off = 1; off < 16; off <<= 1) {
        acc0 += __shfl_xor(acc0, off, 64);
        acc1 += __shfl_xor(acc1, off, 64);
    }

    __shared__ float red[4][CC];
    if (p == 0) {
        red[wv][2 * g + 0] = acc0;
        red[wv][2 * g + 1] = acc1;
    }
    __syncthreads();
    if (tid < CC) {
        const float v = red[0][tid] + red[1][tid] + red[2][tid] + red[3][tid];
        out[((size_t)b * XX + xi) * CC + tid] = v * (1.0f / SS);
    }
}

extern "C" void kernel_launch(void* const* d_in, const int* in_sizes, int n_in,
                              void* d_out, int out_size, void* d_ws, size_t ws_size,
                              hipStream_t stream) {
    const float* yu    = (const float*)d_in[0];
    const float* x     = (const float*)d_in[1];
    const float* W_in  = (const float*)d_in[2];
    const float* b_in  = (const float*)d_in[3];
    const float* W_hid = (const float*)d_in[4];
    const float* b_hid = (const float*)d_in[5];
    const float* W_out = (const float*)d_in[6];
    const float* b_out = (const float*)d_in[7];
    float* out = (float*)d_out;

    dim3 grid(BB * XX);
    dim3 block(256);
    ccl_kernel<<<grid, block, 0, stream>>>(yu, x, W_in, b_in, W_hid, b_hid,
                                           W_out, b_out, out);
}

// Round 3
// 98.523 us; speedup vs baseline: 4.0007x; 1.4613x over previous
//
#include <hip/hip_runtime.h>
#include <math.h>

#define BB 4
#define SS 1024
#define XX 1024
#define CC 8
#define DD 2
#define WIDTH 16
#define DEPTH 4

#define NLUT 8192
#define RSCALE 32.0f          // grid spacing 1/32, domain [0, 256)

// tanh(v) = copysign(2/(1+exp(-2|v|)) - 1, v)
__device__ __forceinline__ float fast_tanh(float v) {
    float ax = __builtin_fabsf(v);
    float e  = __builtin_amdgcn_exp2f(ax * -2.885390081777927f); // exp(-2|v|)
    float t  = fmaf(2.0f, __builtin_amdgcn_rcpf(1.0f + e), -1.0f);
    return __builtin_copysignf(t, v);
}

// ---- kernel 1: tabulate k = f(r) on a uniform grid (fp32 MLP, exact path) ----
__global__ __launch_bounds__(256) void build_lut(
    const float* __restrict__ W_in, const float* __restrict__ b_in,
    const float* __restrict__ W_hid, const float* __restrict__ b_hid,
    const float* __restrict__ W_out, const float* __restrict__ b_out,
    float* __restrict__ lut)
{
    const int idx = blockIdx.x * 256 + threadIdx.x;
    if (idx >= NLUT) return;
    const float r = (float)idx * (1.0f / RSCALE);

    float h[WIDTH];
#pragma unroll
    for (int j = 0; j < WIDTH; ++j) h[j] = fmaf(r, W_in[j], b_in[j]);

#pragma unroll
    for (int l = 0; l < DEPTH; ++l) {
        const float* W  = W_hid + l * WIDTH * WIDTH;
        const float* bb = b_hid + l * WIDTH;
        float pre[WIDTH];
#pragma unroll
        for (int j = 0; j < WIDTH; ++j) pre[j] = bb[j];
#pragma unroll
        for (int i = 0; i < WIDTH; ++i) {
            const float hi = h[i];
#pragma unroll
            for (int j = 0; j < WIDTH; ++j)
                pre[j] = fmaf(hi, W[i * WIDTH + j], pre[j]);
        }
#pragma unroll
        for (int j = 0; j < WIDTH; ++j) h[j] += fast_tanh(pre[j]);
    }

    float k = b_out[0];
#pragma unroll
    for (int j = 0; j < WIDTH; ++j) k = fmaf(h[j], W_out[j], k);
    lut[idx] = k;
}

// ---- kernel 2: per (b,xi) block — LUT gather + weighted accumulation ----
__global__ __launch_bounds__(256) void ccl_main(
    const float* __restrict__ yu,     // (B,S,C+D)
    const float* __restrict__ x,      // (B,X,D)
    const float* __restrict__ lut_g,  // (NLUT)
    float* __restrict__ out)          // (B,X,C)
{
    __shared__ float lut_s[NLUT];     // 32 KB; tail reused for reduction

    const int bx  = blockIdx.x;
    const int b   = bx >> 10;         // X = 1024
    const int xi  = bx & (XX - 1);
    const int tid = threadIdx.x;

    // stage LUT: 8 iterations of float4 (coalesced, ds_write_b128)
    {
        const float4* src = reinterpret_cast<const float4*>(lut_g);
        float4*       dst = reinterpret_cast<float4*>(lut_s);
#pragma unroll
        for (int i = 0; i < NLUT / 4 / 256; ++i)
            dst[tid + i * 256] = src[tid + i * 256];
    }

    const float px0 = x[((size_t)b * XX + xi) * DD + 0];
    const float px1 = x[((size_t)b * XX + xi) * DD + 1];
    const float* yub = yu + (size_t)b * SS * (CC + DD);

    __syncthreads();

    float acc[CC];
#pragma unroll
    for (int c = 0; c < CC; ++c) acc[c] = 0.0f;

#pragma unroll
    for (int t = 0; t < SS / 256; ++t) {
        const int s = tid + t * 256;
        const float2* row = reinterpret_cast<const float2*>(yub + (size_t)s * (CC + DD));
        float2 a0 = row[0], a1 = row[1], a2 = row[2], a3 = row[3], a4 = row[4];

        const float d0 = px0 - a4.x;
        const float d1 = px1 - a4.y;
        const float r  = fmaf(d0, d0, d1 * d1);

        float rf = r * RSCALE;
        int   i  = (int)rf;
        i = min(i, NLUT - 2);
        const float w  = rf - (float)i;
        const float f0 = lut_s[i];
        const float f1 = lut_s[i + 1];
        const float k  = fmaf(w, f1 - f0, f0);

        acc[0] = fmaf(k, a0.x, acc[0]);
        acc[1] = fmaf(k, a0.y, acc[1]);
        acc[2] = fmaf(k, a1.x, acc[2]);
        acc[3] = fmaf(k, a1.y, acc[3]);
        acc[4] = fmaf(k, a2.x, acc[4]);
        acc[5] = fmaf(k, a2.y, acc[5]);
        acc[6] = fmaf(k, a3.x, acc[6]);
        acc[7] = fmaf(k, a3.y, acc[7]);
    }

    // wave reduction (width 64)
#pragma unroll
    for (int c = 0; c < CC; ++c) {
        float v = acc[c];
#pragma unroll
        for (int off = 32; off > 0; off >>= 1)
            v += __shfl_down(v, off, 64);
        acc[c] = v;
    }

    // cross-wave via reused LDS (all lookups are done; barrier first)
    __syncthreads();
    const int lane = tid & 63;
    const int wv   = tid >> 6;
    if (lane == 0) {
#pragma unroll
        for (int c = 0; c < CC; ++c) lut_s[wv * CC + c] = acc[c];
    }
    __syncthreads();
    if (tid < CC) {
        const float v = lut_s[0 * CC + tid] + lut_s[1 * CC + tid] +
                        lut_s[2 * CC + tid] + lut_s[3 * CC + tid];
        out[((size_t)b * XX + xi) * CC + tid] = v * (1.0f / SS);
    }
}

extern "C" void kernel_launch(void* const* d_in, const int* in_sizes, int n_in,
                              void* d_out, int out_size, void* d_ws, size_t ws_size,
                              hipStream_t stream) {
    const float* yu    = (const float*)d_in[0];
    const float* x     = (const float*)d_in[1];
    const float* W_in  = (const float*)d_in[2];
    const float* b_in  = (const float*)d_in[3];
    const float* W_hid = (const float*)d_in[4];
    const float* b_hid = (const float*)d_in[5];
    const float* W_out = (const float*)d_in[6];
    const float* b_out = (const float*)d_in[7];
    float* out = (float*)d_out;
    float* lut = (float*)d_ws;        // 32 KB of scratch

    build_lut<<<dim3(NLUT / 256), dim3(256), 0, stream>>>(
        W_in, b_in, W_hid, b_hid, W_out, b_out, lut);

    ccl_main<<<dim3(BB * XX), dim3(256), 0, stream>>>(yu, x, lut, out);
}

// Round 4
// 94.965 us; speedup vs baseline: 4.1506x; 1.0375x over previous
//
#include <hip/hip_runtime.h>
#include <math.h>

#define BB 4
#define SS 1024
#define XX 1024
#define CC 8
#define DD 2
#define WIDTH 16
#define DEPTH 4

#define NLUT 8192
#define RSCALE 32.0f          // grid spacing 1/32, domain [0, 256)
#define GQ 8                  // queries per block

// tanh(v) = copysign(2/(1+exp(-2|v|)) - 1, v)
__device__ __forceinline__ float fast_tanh(float v) {
    float ax = __builtin_fabsf(v);
    float e  = __builtin_amdgcn_exp2f(ax * -2.885390081777927f); // exp(-2|v|)
    float t  = fmaf(2.0f, __builtin_amdgcn_rcpf(1.0f + e), -1.0f);
    return __builtin_copysignf(t, v);
}

// ---- kernel 1: tabulate k = f(r) on a uniform grid (fp32 MLP, exact path) ----
__global__ __launch_bounds__(256) void build_lut(
    const float* __restrict__ W_in, const float* __restrict__ b_in,
    const float* __restrict__ W_hid, const float* __restrict__ b_hid,
    const float* __restrict__ W_out, const float* __restrict__ b_out,
    float* __restrict__ lut)
{
    const int idx = blockIdx.x * 256 + threadIdx.x;
    if (idx >= NLUT) return;
    const float r = (float)idx * (1.0f / RSCALE);

    float h[WIDTH];
#pragma unroll
    for (int j = 0; j < WIDTH; ++j) h[j] = fmaf(r, W_in[j], b_in[j]);

#pragma unroll
    for (int l = 0; l < DEPTH; ++l) {
        const float* W  = W_hid + l * WIDTH * WIDTH;
        const float* bb = b_hid + l * WIDTH;
        float pre[WIDTH];
#pragma unroll
        for (int j = 0; j < WIDTH; ++j) pre[j] = bb[j];
#pragma unroll
        for (int i = 0; i < WIDTH; ++i) {
            const float hi = h[i];
#pragma unroll
            for (int j = 0; j < WIDTH; ++j)
                pre[j] = fmaf(hi, W[i * WIDTH + j], pre[j]);
        }
#pragma unroll
        for (int j = 0; j < WIDTH; ++j) h[j] += fast_tanh(pre[j]);
    }

    float k = b_out[0];
#pragma unroll
    for (int j = 0; j < WIDTH; ++j) k = fmaf(h[j], W_out[j], k);
    lut[idx] = k;
}

// ---- kernel 2: block = 8 query points; yu rows pinned in registers ----
__global__ __launch_bounds__(256) void ccl_main(
    const float* __restrict__ yu,     // (B,S,C+D)
    const float* __restrict__ x,      // (B,X,D)
    const float* __restrict__ lut_g,  // (NLUT)
    float* __restrict__ out)          // (B,X,C)
{
    __shared__ float lut_s[NLUT];     // 32 KB
    __shared__ float red[4][CC];

    const int bx  = blockIdx.x;
    const int b   = bx / (XX / GQ);           // 512 blocks: 128 per batch
    const int xi0 = (bx % (XX / GQ)) * GQ;
    const int tid = threadIdx.x;

    // stage LUT: 8 iterations of float4 per thread (coalesced)
    {
        const float4* src = reinterpret_cast<const float4*>(lut_g);
        float4*       dst = reinterpret_cast<float4*>(lut_s);
#pragma unroll
        for (int i = 0; i < NLUT / 4 / 256; ++i)
            dst[tid + i * 256] = src[tid + i * 256];
    }

    // pin this thread's 4 s-points (y and u) in registers
    const float* yub = yu + (size_t)b * SS * (CC + DD);
    float2 yp[4];
    float  up[4][CC];
#pragma unroll
    for (int i = 0; i < 4; ++i) {
        const int s = tid + i * 256;
        const float2* row = reinterpret_cast<const float2*>(yub + (size_t)s * (CC + DD));
        float2 a0 = row[0], a1 = row[1], a2 = row[2], a3 = row[3];
        yp[i] = row[4];
        up[i][0] = a0.x; up[i][1] = a0.y; up[i][2] = a1.x; up[i][3] = a1.y;
        up[i][4] = a2.x; up[i][5] = a2.y; up[i][6] = a3.x; up[i][7] = a3.y;
    }

    // query coords (block-uniform)
    const float* xp = x + ((size_t)b * XX + xi0) * DD;

    __syncthreads();

    const int lane = tid & 63;
    const int wv   = tid >> 6;

#pragma unroll
    for (int q = 0; q < GQ; ++q) {
        const float px0 = xp[2 * q + 0];
        const float px1 = xp[2 * q + 1];

        float acc[CC];
#pragma unroll
        for (int c = 0; c < CC; ++c) acc[c] = 0.0f;

#pragma unroll
        for (int i = 0; i < 4; ++i) {
            const float d0 = px0 - yp[i].x;
            const float d1 = px1 - yp[i].y;
            const float r  = fmaf(d0, d0, d1 * d1);

            float rf = r * RSCALE;
            int   ix = (int)rf;
            ix = min(ix, NLUT - 2);
            const float w  = rf - (float)ix;
            const float f0 = lut_s[ix];
            const float f1 = lut_s[ix + 1];
            const float k  = fmaf(w, f1 - f0, f0);

#pragma unroll
            for (int c = 0; c < CC; ++c) acc[c] = fmaf(k, up[i][c], acc[c]);
        }

        // wave reduction (width 64)
#pragma unroll
        for (int c = 0; c < CC; ++c) {
            float v = acc[c];
#pragma unroll
            for (int off = 32; off > 0; off >>= 1)
                v += __shfl_down(v, off, 64);
            acc[c] = v;
        }

        __syncthreads();                 // red free from previous query
        if (lane == 0) {
#pragma unroll
            for (int c = 0; c < CC; ++c) red[wv][c] = acc[c];
        }
        __syncthreads();
        if (tid < CC) {
            const float v = red[0][tid] + red[1][tid] + red[2][tid] + red[3][tid];
            out[((size_t)b * XX + xi0 + q) * CC + tid] = v * (1.0f / SS);
        }
    }
}

extern "C" void kernel_launch(void* const* d_in, const int* in_sizes, int n_in,
                              void* d_out, int out_size, void* d_ws, size_t ws_size,
                              hipStream_t stream) {
    const float* yu    = (const float*)d_in[0];
    const float* x     = (const float*)d_in[1];
    const float* W_in  = (const float*)d_in[2];
    const float* b_in  = (const float*)d_in[3];
    const float* W_hid = (const float*)d_in[4];
    const float* b_hid = (const float*)d_in[5];
    const float* W_out = (const float*)d_in[6];
    const float* b_out = (const float*)d_in[7];
    float* out = (float*)d_out;
    float* lut = (float*)d_ws;        // 32 KB of scratch

    build_lut<<<dim3(NLUT / 256), dim3(256), 0, stream>>>(
        W_in, b_in, W_hid, b_hid, W_out, b_out, lut);

    ccl_main<<<dim3(BB * XX / GQ), dim3(256), 0, stream>>>(yu, x, lut, out);
}